// Round 1
// baseline (201.778 us; speedup 1.0000x reference)
//
#include <hip/hip_runtime.h>
#include <math.h>

typedef __bf16 bf16_t;
typedef __bf16 bf16x4 __attribute__((ext_vector_type(4)));
typedef __bf16 bf16x8 __attribute__((ext_vector_type(8)));
typedef float  f32x4  __attribute__((ext_vector_type(4)));
typedef float  f32x8  __attribute__((ext_vector_type(8)));

#define NHEADS 16
#define DH 64
#define SEQ 2048
#define DMODEL 1024

static __device__ __forceinline__ f32x4 mfma_bf16(bf16x8 a, bf16x8 b, f32x4 c) {
  return __builtin_amdgcn_mfma_f32_16x16x32_bf16(a, b, c, 0, 0, 0);
}

// async global->LDS, 16B per lane; LDS dest = wave-uniform base + lane*16
static __device__ __forceinline__ void load_lds16(const bf16_t* g, bf16_t* l) {
  __builtin_amdgcn_global_load_lds(
      (const __attribute__((address_space(1))) void*)g,
      (__attribute__((address_space(3))) void*)l, 16, 0, 0);
}

// ---------------- f32 -> bf16 pre-convert ----------------
// flat dst layout: x(4M) | Wq(1M) | Wk(1M) | Wv(1M) | Wo(1M) elems
__global__ __launch_bounds__(256) void convert_kernel(
    const float* __restrict__ x, const float* __restrict__ Wq,
    const float* __restrict__ Wk, const float* __restrict__ Wv,
    const float* __restrict__ Wo, bf16_t* __restrict__ dst)
{
  const size_t idx = ((size_t)blockIdx.x * 256 + threadIdx.x) * 8;
  const size_t XN = (size_t)4096 * DMODEL;
  const float* src;
  size_t off;
  if (idx < XN) { src = x; off = idx; }
  else {
    size_t r = idx - XN;
    int q = (int)(r >> 20);
    off = r & ((size_t)(1u << 20) - 1);
    src = (q == 0) ? Wq : (q == 1) ? Wk : (q == 2) ? Wv : Wo;
  }
  f32x8 v = *(const f32x8*)(src + off);
  bf16x8 o;
  #pragma unroll
  for (int j = 0; j < 8; ++j) o[j] = (bf16_t)v[j];
  *(bf16x8*)(dst + idx) = o;
}

// ---------------- shared 128x128 GEMM core (m97 structure + LDS swizzle) ----
// K/V-style XOR swizzle (guide rule 21): global_load_lds writes linearly, so
// the 16B source chunk is pre-permuted (sc ^ sr&3) and ds_read applies the
// same XOR (quad ^ row&3). Post-swizzle each half-wave b128 read spreads over
// all 32 banks, 4 lanes/bank = cycle floor (was 8 lanes on 16 banks).
static __device__ __forceinline__ void gemm128(
    const bf16_t* __restrict__ A, const bf16_t* __restrict__ B,
    bf16_t* As, bf16_t* Bs, f32x4 (&acc)[4][4])
{
  const int t    = threadIdx.x;
  const int w    = t >> 6;
  const int lane = t & 63;
  const int col  = lane & 15;
  const int quad = lane >> 4;
  const int wm   = w >> 1;
  const int wn   = w & 1;

  const int sr = t >> 2;
  const int sc = (t & 3) ^ (sr & 3);          // swizzled source chunk
  const bf16_t* ga = A + (size_t)sr * DMODEL + sc * 8;
  const bf16_t* gb = B + (size_t)sr * DMODEL + sc * 8;
  bf16_t* la = As + w * 512;
  bf16_t* lb = Bs + w * 512;

  const int swz = (quad ^ (col & 3)) * 8;     // read-side XOR (row&3 == col&3)

  for (int kk = 0; kk < DMODEL; kk += 32) {
    load_lds16(ga + kk, la);
    load_lds16(ga + (size_t)64 * DMODEL + kk, la + 2048);
    load_lds16(gb + kk, lb);
    load_lds16(gb + (size_t)64 * DMODEL + kk, lb + 2048);
    __syncthreads();

    bf16x8 af[4], bfr[4];
    #pragma unroll
    for (int i = 0; i < 4; ++i) {
      af[i]  = *(const bf16x8*)(As + (wm * 64 + i * 16 + col) * 32 + swz);
      bfr[i] = *(const bf16x8*)(Bs + (wn * 64 + i * 16 + col) * 32 + swz);
    }
    #pragma unroll
    for (int mt = 0; mt < 4; ++mt)
      #pragma unroll
      for (int nt = 0; nt < 4; ++nt)
        acc[mt][nt] = mfma_bf16(af[mt], bfr[nt], acc[mt][nt]);
    __syncthreads();
  }
}

// ---------------- QKV projection ----------------
__global__ __launch_bounds__(256) void qkv_gemm_kernel(
    const bf16_t* __restrict__ xb, const bf16_t* __restrict__ Wall,
    bf16_t* __restrict__ Qb, bf16_t* __restrict__ Kb, bf16_t* __restrict__ Vt)
{
  __shared__ __align__(16) bf16_t As[128 * 32];
  __shared__ __align__(16) bf16_t Bs[128 * 32];
  f32x4 acc[4][4] = {};
  const int m0 = blockIdx.x * 128;
  const int n0 = blockIdx.y * 128;
  gemm128(xb + (size_t)m0 * DMODEL, Wall + (size_t)n0 * DMODEL, As, Bs, acc);

  const int t = threadIdx.x;
  const int lane = t & 63, w = t >> 6;
  const int col = lane & 15, quad = lane >> 4;
  const int wm = w >> 1, wn = w & 1;
  const int nw0 = n0 + wn * 64;
  const int wt  = nw0 >> 10;          // 0=Q, 1=K, 2=V
  const int h   = (nw0 >> 6) & 15;
  const int mbase = m0 + wm * 64;

  if (wt < 2) {
    bf16_t* Out = (wt == 0) ? Qb : Kb;
    #pragma unroll
    for (int mt = 0; mt < 4; ++mt) {
      #pragma unroll
      for (int nt = 0; nt < 4; ++nt) {
        const int d = nt * 16 + col;
        #pragma unroll
        for (int r = 0; r < 4; ++r) {
          const int m = mbase + mt * 16 + quad * 4 + r;
          const int b = m >> 11, s = m & (SEQ - 1);
          Out[((size_t)(b * NHEADS + h) * SEQ + s) * DH + d] = (bf16_t)acc[mt][nt][r];
        }
      }
    }
  } else {
    #pragma unroll
    for (int mt = 0; mt < 4; ++mt) {
      const int m = mbase + mt * 16 + quad * 4;
      const int b = m >> 11, s = m & (SEQ - 1);
      #pragma unroll
      for (int nt = 0; nt < 4; ++nt) {
        const int d = nt * 16 + col;
        bf16x4 v4 = { (bf16_t)acc[mt][nt][0], (bf16_t)acc[mt][nt][1],
                      (bf16_t)acc[mt][nt][2], (bf16_t)acc[mt][nt][3] };
        *(bf16x4*)(Vt + ((size_t)(b * NHEADS + h) * DH + d) * SEQ + s) = v4;
      }
    }
  }
}

// ---------------- RoPE (in-place on Q and K) ----------------
__global__ __launch_bounds__(256) void rope_kernel(
    bf16_t* __restrict__ Qb, bf16_t* __restrict__ Kb, const int* __restrict__ tpos)
{
  const int idx = blockIdx.x * 256 + threadIdx.x;
  const int i  = idx & 31;
  const int s  = (idx >> 5) & (SEQ - 1);
  const int bh = idx >> 16;

  const float pos  = (float)tpos[s];
  const float freq = expf((float)i * -0.28782313662425573f);
  const float ang  = pos * freq;
  const float cs = cosf(ang), sn = sinf(ang);

  const size_t base = ((size_t)bh * SEQ + s) * DH + 2 * i;
  {
    float e = (float)Qb[base], o = (float)Qb[base + 1];
    Qb[base]     = (bf16_t)(e * cs - o * sn);
    Qb[base + 1] = (bf16_t)(e * sn + o * cs);
  }
  {
    float e = (float)Kb[base], o = (float)Kb[base + 1];
    Kb[base]     = (bf16_t)(e * cs - o * sn);
    Kb[base + 1] = (bf16_t)(e * sn + o * cs);
  }
}

// ---------------- Flash attention v7 ----------------
// v6 -> v7: (1) 32 q-rows per wave (2 q-groups per B-operand side): K/V LDS
// bytes per unit work halved, MFMA per LDS byte doubled. q-tiles are 128 rows,
// paired (qt, 15-qt) -> grid (32,8), constant 34 k-iters/block, 1 block/CU.
// (2) K/V LDS XOR swizzle: source chunk ^ (row&3) at stage time (LDS dest must
// stay linear for global_load_lds), read addr chunk = quad ^ (row&3). Each
// half-wave ds_read_b128 now hits all 32 banks 4x (floor); was 16 banks 8x.
// (3) waves 0/1 skip the phase-final k-tile (fully masked for their rows).
// P layout unchanged from v6 (already bank-balanced), duplicated per q-group.
__global__ __launch_bounds__(256) void attn_kernel(
    const bf16_t* __restrict__ Qb, const bf16_t* __restrict__ Kb,
    const bf16_t* __restrict__ Vt, bf16_t* __restrict__ attn)
{
  __shared__ __align__(16) bf16_t Ks[2][4096];   // 2 planes x (64 keys x 32)
  __shared__ __align__(16) bf16_t Vs[2][4096];
  __shared__ __align__(16) bf16_t Ps[4][2560];   // per wave: 2 qgrp x 2 planes x 640

  const int t    = threadIdx.x;
  const int wave = t >> 6;
  const int lane = t & 63;
  const int col  = lane & 15;
  const int quad = lane >> 4;
  const int bh = blockIdx.x;
  const int h  = bh & 15;
  const int b  = bh >> 4;
  const int qtA = blockIdx.y;          // 0..7
  const int qtB = 15 - qtA;            // 8..15

  const size_t hoff = (size_t)(b * NHEADS + h) * SEQ * DH;
  const bf16_t* Qh = Qb + hoff;
  const bf16_t* Kh = Kb + hoff;
  const bf16_t* Vh = Vt + hoff;                // (d,s), row stride SEQ

  // Q B-fragments: 2 q-groups x 2 k-chunks per phase, pre-scaled 1/8*log2(e)
  const int qrA = qtA * 128 + wave * 32 + col;
  const int qrB = qtB * 128 + wave * 32 + col;
  bf16x8 qA00 = *(const bf16x8*)(Qh + (size_t)qrA * DH + quad * 8);
  bf16x8 qA01 = *(const bf16x8*)(Qh + (size_t)qrA * DH + 32 + quad * 8);
  bf16x8 qA10 = *(const bf16x8*)(Qh + (size_t)(qrA + 16) * DH + quad * 8);
  bf16x8 qA11 = *(const bf16x8*)(Qh + (size_t)(qrA + 16) * DH + 32 + quad * 8);
  bf16x8 qB00 = *(const bf16x8*)(Qh + (size_t)qrB * DH + quad * 8);
  bf16x8 qB01 = *(const bf16x8*)(Qh + (size_t)qrB * DH + 32 + quad * 8);
  bf16x8 qB10 = *(const bf16x8*)(Qh + (size_t)(qrB + 16) * DH + quad * 8);
  bf16x8 qB11 = *(const bf16x8*)(Qh + (size_t)(qrB + 16) * DH + 32 + quad * 8);
  #pragma unroll
  for (int j = 0; j < 8; ++j) {
    const float sc = 0.1803368801111191f;
    qA00[j] = (bf16_t)((float)qA00[j] * sc); qA01[j] = (bf16_t)((float)qA01[j] * sc);
    qA10[j] = (bf16_t)((float)qA10[j] * sc); qA11[j] = (bf16_t)((float)qA11[j] * sc);
    qB00[j] = (bf16_t)((float)qB00[j] * sc); qB01[j] = (bf16_t)((float)qB01[j] * sc);
    qB10[j] = (bf16_t)((float)qB10[j] * sc); qB11[j] = (bf16_t)((float)qB11[j] * sc);
  }

  // staging map: thread t -> row t>>2, swizzled 16B chunk; dst = base + t*16B
  const int sr  = t >> 2;
  const int scs = (t & 3) ^ (sr & 3);          // swizzled source chunk
  const int lbase = t * 8;                     // elems
  const bf16_t* kg0 = Kh + (size_t)sr * DH + scs * 8;
  const bf16_t* vg0 = Vh + (size_t)sr * SEQ + scs * 8;

  // prologue: stage k-tile 0 into buf 0
  load_lds16(kg0,      &Ks[0][lbase]);
  load_lds16(kg0 + 32, &Ks[0][2048 + lbase]);
  load_lds16(vg0,      &Vs[0][lbase]);
  load_lds16(vg0 + 32, &Vs[0][2048 + lbase]);

  f32x4 o[4][2] = {};
  float lsum0 = 0.0f, lsum1 = 0.0f;
  bf16_t* P = Ps[wave];
  const int pwoff = col * 40 + quad * 4;
  const int kswz  = (quad ^ (col & 3)) * 8;    // K/V read-side XOR
  const int wk = wave & 1;                     // q offset within diag tile /32
  const int wh = wave >> 1;                    // which 64-key half is diagonal

  bf16x8 q00 = qA00, q01 = qA01, q10 = qA10, q11 = qA11;
  int qcur = qtA;
  int it = 0;
  int phaseEnd = 2 * qtA + 1;
  int dtile = 2 * qtA + wh;

  for (int g = 0; g < 34; ++g) {
    const int buf = g & 1;
    __syncthreads();   // DMA for tile g complete; buf^1 free

    if (g < 33) {      // prefetch next k-tile (tile 0 of phase B at phase end)
      const int nk = (it == phaseEnd) ? 0 : (it + 1);
      const bf16_t* kg = kg0 + (size_t)nk * 64 * DH;
      const bf16_t* vg = vg0 + nk * 64;
      bf16_t* Kd = Ks[buf ^ 1];
      bf16_t* Vd = Vs[buf ^ 1];
      load_lds16(kg,      Kd + lbase);
      load_lds16(kg + 32, Kd + 2048 + lbase);
      load_lds16(vg,      Vd + lbase);
      load_lds16(vg + 32, Vd + 2048 + lbase);
    }

    if (it <= dtile) {                 // waves 0/1 skip phase-final tile
      const bool diag = (it == dtile);
      const bf16_t* Kbuf = Ks[buf];

      // QK^T (rows=keys, cols=q) + softmax -> P
      #pragma unroll
      for (int kt = 0; kt < 4; ++kt) {
        const int R = 16 * kt + col;
        bf16x8 ka = *(const bf16x8*)(Kbuf + R * 32 + kswz);
        bf16x8 kb = *(const bf16x8*)(Kbuf + 2048 + R * 32 + kswz);
        f32x4 s0 = {}, s1 = {};
        s0 = mfma_bf16(ka, q00, s0);
        s0 = mfma_bf16(kb, q01, s0);
        s1 = mfma_bf16(ka, q10, s1);
        s1 = mfma_bf16(kb, q11, s1);
        const int kl = kt * 16 + quad * 4;
        bf16x4 p40, p41;
        #pragma unroll
        for (int r = 0; r < 4; ++r) {
          float p0 = (!diag || (kl + r <= wk * 32 + col))
                         ? __builtin_amdgcn_exp2f(s0[r]) : 0.0f;
          float p1 = (!diag || (kl + r <= wk * 32 + 16 + col))
                         ? __builtin_amdgcn_exp2f(s1[r]) : 0.0f;
          lsum0 += p0; lsum1 += p1;
          p40[r] = (bf16_t)p0; p41[r] = (bf16_t)p1;
        }
        *(bf16x4*)(P + (kt >> 1) * 640 + (kt & 1) * 16 + pwoff) = p40;
        *(bf16x4*)(P + 1280 + (kt >> 1) * 640 + (kt & 1) * 16 + pwoff) = p41;
      }

      // P B-fragments (balanced-bank b128 reads)
      bf16x8 pf00 = *(const bf16x8*)(P + col * 40 + quad * 8);
      bf16x8 pf01 = *(const bf16x8*)(P + 640 + col * 40 + quad * 8);
      bf16x8 pf10 = *(const bf16x8*)(P + 1280 + col * 40 + quad * 8);
      bf16x8 pf11 = *(const bf16x8*)(P + 1920 + col * 40 + quad * 8);

      // PV: o[d][q] += V' * P
      const bf16_t* Vbuf = Vs[buf];
      #pragma unroll
      for (int dt = 0; dt < 4; ++dt) {
        const int R = 16 * dt + col;
        bf16x8 va = *(const bf16x8*)(Vbuf + R * 32 + kswz);
        bf16x8 vb = *(const bf16x8*)(Vbuf + 2048 + R * 32 + kswz);
        o[dt][0] = mfma_bf16(va, pf00, o[dt][0]);
        o[dt][0] = mfma_bf16(vb, pf01, o[dt][0]);
        o[dt][1] = mfma_bf16(va, pf10, o[dt][1]);
        o[dt][1] = mfma_bf16(vb, pf11, o[dt][1]);
      }
    }

    if (it == phaseEnd) {
      // finalize current phase: reduce lsum across quads, normalize, store
      float ls0 = lsum0, ls1 = lsum1;
      ls0 += __shfl_xor(ls0, 16, 64);
      ls0 += __shfl_xor(ls0, 32, 64);
      ls1 += __shfl_xor(ls1, 16, 64);
      ls1 += __shfl_xor(ls1, 32, 64);
      const float inv0 = 1.0f / ls0;
      const float inv1 = 1.0f / ls1;
      const int q0r = qcur * 128 + wave * 32 + col;
      const size_t orow0 = (size_t)(b * SEQ + q0r) * DMODEL + h * DH;
      const size_t orow1 = (size_t)(b * SEQ + q0r + 16) * DMODEL + h * DH;
      #pragma unroll
      for (int dt = 0; dt < 4; ++dt) {
        bf16x4 v0 = { (bf16_t)(o[dt][0][0] * inv0), (bf16_t)(o[dt][0][1] * inv0),
                      (bf16_t)(o[dt][0][2] * inv0), (bf16_t)(o[dt][0][3] * inv0) };
        bf16x4 v1 = { (bf16_t)(o[dt][1][0] * inv1), (bf16_t)(o[dt][1][1] * inv1),
                      (bf16_t)(o[dt][1][2] * inv1), (bf16_t)(o[dt][1][3] * inv1) };
        *(bf16x4*)(attn + orow0 + dt * 16 + quad * 4) = v0;
        *(bf16x4*)(attn + orow1 + dt * 16 + quad * 4) = v1;
      }
      // switch to phase B
      #pragma unroll
      for (int dt = 0; dt < 4; ++dt) {
        o[dt][0] = f32x4{};
        o[dt][1] = f32x4{};
      }
      lsum0 = 0.0f; lsum1 = 0.0f;
      q00 = qB00; q01 = qB01; q10 = qB10; q11 = qB11;
      qcur = qtB;
      it = 0;
      phaseEnd = 2 * qtB + 1;
      dtile = 2 * qtB + wh;
    } else {
      ++it;
    }
  }
}

// ---------------- Output projection (-> f32 d_out) ----------------
__global__ __launch_bounds__(256) void out_gemm_kernel(
    const bf16_t* __restrict__ Ab, const bf16_t* __restrict__ Wob,
    float* __restrict__ out)
{
  __shared__ __align__(16) bf16_t As[128 * 32];
  __shared__ __align__(16) bf16_t Bs[128 * 32];
  f32x4 acc[4][4] = {};
  const int m0 = blockIdx.x * 128;
  const int n0 = blockIdx.y * 128;
  gemm128(Ab + (size_t)m0 * DMODEL, Wob + (size_t)n0 * DMODEL, As, Bs, acc);

  const int t = threadIdx.x;
  const int lane = t & 63, w = t >> 6;
  const int col = lane & 15, quad = lane >> 4;
  const int wm = w >> 1, wn = w & 1;
  const int mbase = m0 + wm * 64;
  const int nbase = n0 + wn * 64;

  #pragma unroll
  for (int mt = 0; mt < 4; ++mt)
    #pragma unroll
    for (int nt = 0; nt < 4; ++nt)
      #pragma unroll
      for (int r = 0; r < 4; ++r)
        out[(size_t)(mbase + mt * 16 + quad * 4 + r) * DMODEL + nbase + nt * 16 + col] =
            acc[mt][nt][r];
}

extern "C" void kernel_launch(void* const* d_in, const int* in_sizes, int n_in,
                              void* d_out, int out_size, void* d_ws, size_t ws_size,
                              hipStream_t stream)
{
  (void)in_sizes; (void)n_in; (void)out_size; (void)ws_size;
  const float* x  = (const float*)d_in[0];
  const float* Wq = (const float*)d_in[1];
  const float* Wk = (const float*)d_in[2];
  const float* Wv = (const float*)d_in[3];
  const float* Wo = (const float*)d_in[4];
  const int* tpos = (const int*)d_in[5];
  float* out = (float*)d_out;

  const size_t M1 = (size_t)1024 * 1024;
  bf16_t* xb    = (bf16_t*)d_ws;                  // 4M elems
  bf16_t* Wall  = xb + 4 * M1;                    // Wq|Wk|Wv (3M)
  bf16_t* Wob   = xb + 7 * M1;                    // 1M
  bf16_t* Qb    = xb + 8 * M1;                    // 4M  (b,h,s,d)
  bf16_t* Kb    = Qb + 4 * M1;                    // 4M  (b,h,s,d)
  bf16_t* Vt    = Kb + 4 * M1;                    // 4M  (b,h,d,s)
  bf16_t* attnb = Vt + 4 * M1;                    // 4M  (b*s, h*d)

  convert_kernel<<<dim3(4096, 1, 1), dim3(256, 1, 1), 0, stream>>>(
      x, Wq, Wk, Wv, Wo, xb);
  qkv_gemm_kernel<<<dim3(32, 24, 1), dim3(256, 1, 1), 0, stream>>>(
      xb, Wall, Qb, Kb, Vt);
  rope_kernel<<<dim3(8192, 1, 1), dim3(256, 1, 1), 0, stream>>>(Qb, Kb, tpos);
  attn_kernel<<<dim3(32, 8, 1), dim3(256, 1, 1), 0, stream>>>(
      Qb, Kb, Vt, attnb);
  out_gemm_kernel<<<dim3(32, 8, 1), dim3(256, 1, 1), 0, stream>>>(
      attnb, Wob, out);
}

// Round 2
// 195.529 us; speedup vs baseline: 1.0320x; 1.0320x over previous
//
#include <hip/hip_runtime.h>
#include <math.h>

typedef __bf16 bf16_t;
typedef __bf16 bf16x4 __attribute__((ext_vector_type(4)));
typedef __bf16 bf16x8 __attribute__((ext_vector_type(8)));
typedef float  f32x4  __attribute__((ext_vector_type(4)));
typedef float  f32x8  __attribute__((ext_vector_type(8)));

#define NHEADS 16
#define DH 64
#define SEQ 2048
#define DMODEL 1024

static __device__ __forceinline__ f32x4 mfma_bf16(bf16x8 a, bf16x8 b, f32x4 c) {
  return __builtin_amdgcn_mfma_f32_16x16x32_bf16(a, b, c, 0, 0, 0);
}

// async global->LDS, 16B per lane; LDS dest = wave-uniform base + lane*16
static __device__ __forceinline__ void load_lds16(const bf16_t* g, bf16_t* l) {
  __builtin_amdgcn_global_load_lds(
      (const __attribute__((address_space(1))) void*)g,
      (__attribute__((address_space(3))) void*)l, 16, 0, 0);
}

// ---------------- f32 -> bf16 pre-convert ----------------
// flat dst layout: x(4M) | Wq(1M) | Wk(1M) | Wv(1M) | Wo(1M) elems
__global__ __launch_bounds__(256) void convert_kernel(
    const float* __restrict__ x, const float* __restrict__ Wq,
    const float* __restrict__ Wk, const float* __restrict__ Wv,
    const float* __restrict__ Wo, bf16_t* __restrict__ dst)
{
  const size_t idx = ((size_t)blockIdx.x * 256 + threadIdx.x) * 8;
  const size_t XN = (size_t)4096 * DMODEL;
  const float* src;
  size_t off;
  if (idx < XN) { src = x; off = idx; }
  else {
    size_t r = idx - XN;
    int q = (int)(r >> 20);
    off = r & ((size_t)(1u << 20) - 1);
    src = (q == 0) ? Wq : (q == 1) ? Wk : (q == 2) ? Wv : Wo;
  }
  f32x8 v = *(const f32x8*)(src + off);
  bf16x8 o;
  #pragma unroll
  for (int j = 0; j < 8; ++j) o[j] = (bf16_t)v[j];
  *(bf16x8*)(dst + idx) = o;
}

// ---------------- shared 128x128 GEMM core (m97 structure + LDS swizzle) ----
static __device__ __forceinline__ void gemm128(
    const bf16_t* __restrict__ A, const bf16_t* __restrict__ B,
    bf16_t* As, bf16_t* Bs, f32x4 (&acc)[4][4])
{
  const int t    = threadIdx.x;
  const int w    = t >> 6;
  const int lane = t & 63;
  const int col  = lane & 15;
  const int quad = lane >> 4;
  const int wm   = w >> 1;
  const int wn   = w & 1;

  const int sr = t >> 2;
  const int sc = (t & 3) ^ (sr & 3);          // swizzled source chunk
  const bf16_t* ga = A + (size_t)sr * DMODEL + sc * 8;
  const bf16_t* gb = B + (size_t)sr * DMODEL + sc * 8;
  bf16_t* la = As + w * 512;
  bf16_t* lb = Bs + w * 512;

  const int swz = (quad ^ (col & 3)) * 8;     // read-side XOR

  for (int kk = 0; kk < DMODEL; kk += 32) {
    load_lds16(ga + kk, la);
    load_lds16(ga + (size_t)64 * DMODEL + kk, la + 2048);
    load_lds16(gb + kk, lb);
    load_lds16(gb + (size_t)64 * DMODEL + kk, lb + 2048);
    __syncthreads();

    bf16x8 af[4], bfr[4];
    #pragma unroll
    for (int i = 0; i < 4; ++i) {
      af[i]  = *(const bf16x8*)(As + (wm * 64 + i * 16 + col) * 32 + swz);
      bfr[i] = *(const bf16x8*)(Bs + (wn * 64 + i * 16 + col) * 32 + swz);
    }
    #pragma unroll
    for (int mt = 0; mt < 4; ++mt)
      #pragma unroll
      for (int nt = 0; nt < 4; ++nt)
        acc[mt][nt] = mfma_bf16(af[mt], bfr[nt], acc[mt][nt]);
    __syncthreads();
  }
}

// ---------------- QKV projection ----------------
__global__ __launch_bounds__(256) void qkv_gemm_kernel(
    const bf16_t* __restrict__ xb, const bf16_t* __restrict__ Wall,
    bf16_t* __restrict__ Qb, bf16_t* __restrict__ Kb, bf16_t* __restrict__ Vt)
{
  __shared__ __align__(16) bf16_t As[128 * 32];
  __shared__ __align__(16) bf16_t Bs[128 * 32];
  f32x4 acc[4][4] = {};
  const int m0 = blockIdx.x * 128;
  const int n0 = blockIdx.y * 128;
  gemm128(xb + (size_t)m0 * DMODEL, Wall + (size_t)n0 * DMODEL, As, Bs, acc);

  const int t = threadIdx.x;
  const int lane = t & 63, w = t >> 6;
  const int col = lane & 15, quad = lane >> 4;
  const int wm = w >> 1, wn = w & 1;
  const int nw0 = n0 + wn * 64;
  const int wt  = nw0 >> 10;          // 0=Q, 1=K, 2=V
  const int h   = (nw0 >> 6) & 15;
  const int mbase = m0 + wm * 64;

  if (wt < 2) {
    bf16_t* Out = (wt == 0) ? Qb : Kb;
    #pragma unroll
    for (int mt = 0; mt < 4; ++mt) {
      #pragma unroll
      for (int nt = 0; nt < 4; ++nt) {
        const int d = nt * 16 + col;
        #pragma unroll
        for (int r = 0; r < 4; ++r) {
          const int m = mbase + mt * 16 + quad * 4 + r;
          const int b = m >> 11, s = m & (SEQ - 1);
          Out[((size_t)(b * NHEADS + h) * SEQ + s) * DH + d] = (bf16_t)acc[mt][nt][r];
        }
      }
    }
  } else {
    #pragma unroll
    for (int mt = 0; mt < 4; ++mt) {
      const int m = mbase + mt * 16 + quad * 4;
      const int b = m >> 11, s = m & (SEQ - 1);
      #pragma unroll
      for (int nt = 0; nt < 4; ++nt) {
        const int d = nt * 16 + col;
        bf16x4 v4 = { (bf16_t)acc[mt][nt][0], (bf16_t)acc[mt][nt][1],
                      (bf16_t)acc[mt][nt][2], (bf16_t)acc[mt][nt][3] };
        *(bf16x4*)(Vt + ((size_t)(b * NHEADS + h) * DH + d) * SEQ + s) = v4;
      }
    }
  }
}

// ---------------- RoPE (in-place on Q and K) ----------------
__global__ __launch_bounds__(256) void rope_kernel(
    bf16_t* __restrict__ Qb, bf16_t* __restrict__ Kb, const int* __restrict__ tpos)
{
  const int idx = blockIdx.x * 256 + threadIdx.x;
  const int i  = idx & 31;
  const int s  = (idx >> 5) & (SEQ - 1);
  const int bh = idx >> 16;

  const float pos  = (float)tpos[s];
  const float freq = expf((float)i * -0.28782313662425573f);
  const float ang  = pos * freq;
  const float cs = cosf(ang), sn = sinf(ang);

  const size_t base = ((size_t)bh * SEQ + s) * DH + 2 * i;
  {
    float e = (float)Qb[base], o = (float)Qb[base + 1];
    Qb[base]     = (bf16_t)(e * cs - o * sn);
    Qb[base + 1] = (bf16_t)(e * sn + o * cs);
  }
  {
    float e = (float)Kb[base], o = (float)Kb[base + 1];
    Kb[base]     = (bf16_t)(e * cs - o * sn);
    Kb[base + 1] = (bf16_t)(e * sn + o * cs);
  }
}

// ---------------- Flash attention v8 ----------------
// v7 -> v8: one 128-row q-tile per block (no in-block phase pairing).
// Grid (32,16) = 512 blocks restores 2 blocks/CU residency (v7's 256-block
// grid left 1 block/CU, occupancy 10%, every latency exposed -> 59us).
// Load balance via complementary y->qt map (qt = y<8 ? y : 23-y): round-robin
// block->CU placement gives each CU a (qt, 15-qt) pair = 34 iters total.
// Keeps v7's 32 q-rows/wave (halved K/V LDS traffic per work) and K/V swizzle.
// Only one q-tile's fragments loaded (4 bf16x8, was 8) -> lower VGPR.
__global__ __launch_bounds__(256) void attn_kernel(
    const bf16_t* __restrict__ Qb, const bf16_t* __restrict__ Kb,
    const bf16_t* __restrict__ Vt, bf16_t* __restrict__ attn)
{
  __shared__ __align__(16) bf16_t Ks[2][4096];   // 2 planes x (64 keys x 32)
  __shared__ __align__(16) bf16_t Vs[2][4096];
  __shared__ __align__(16) bf16_t Ps[4][2560];   // per wave: 2 qgrp x 2 planes x 640

  const int t    = threadIdx.x;
  const int wave = t >> 6;
  const int lane = t & 63;
  const int col  = lane & 15;
  const int quad = lane >> 4;
  const int bh = blockIdx.x;
  const int h  = bh & 15;
  const int b  = bh >> 4;
  const int by = blockIdx.y;
  const int qt = (by < 8) ? by : (23 - by);      // complementary pairing per CU

  const size_t hoff = (size_t)(b * NHEADS + h) * SEQ * DH;
  const bf16_t* Qh = Qb + hoff;
  const bf16_t* Kh = Kb + hoff;
  const bf16_t* Vh = Vt + hoff;                // (d,s), row stride SEQ

  // Q B-fragments: 2 q-groups x 2 k-chunks, pre-scaled by 1/8 * log2(e)
  const int qr = qt * 128 + wave * 32 + col;
  bf16x8 q00 = *(const bf16x8*)(Qh + (size_t)qr * DH + quad * 8);
  bf16x8 q01 = *(const bf16x8*)(Qh + (size_t)qr * DH + 32 + quad * 8);
  bf16x8 q10 = *(const bf16x8*)(Qh + (size_t)(qr + 16) * DH + quad * 8);
  bf16x8 q11 = *(const bf16x8*)(Qh + (size_t)(qr + 16) * DH + 32 + quad * 8);
  #pragma unroll
  for (int j = 0; j < 8; ++j) {
    const float sc = 0.1803368801111191f;
    q00[j] = (bf16_t)((float)q00[j] * sc); q01[j] = (bf16_t)((float)q01[j] * sc);
    q10[j] = (bf16_t)((float)q10[j] * sc); q11[j] = (bf16_t)((float)q11[j] * sc);
  }

  // staging map: thread t -> row t>>2, swizzled 16B chunk; dst = base + t*16B
  const int sr  = t >> 2;
  const int scs = (t & 3) ^ (sr & 3);          // swizzled source chunk
  const int lbase = t * 8;                     // elems
  const bf16_t* kg0 = Kh + (size_t)sr * DH + scs * 8;
  const bf16_t* vg0 = Vh + (size_t)sr * SEQ + scs * 8;

  // prologue: stage k-tile 0 into buf 0
  load_lds16(kg0,      &Ks[0][lbase]);
  load_lds16(kg0 + 32, &Ks[0][2048 + lbase]);
  load_lds16(vg0,      &Vs[0][lbase]);
  load_lds16(vg0 + 32, &Vs[0][2048 + lbase]);

  f32x4 o[4][2] = {};
  float lsum0 = 0.0f, lsum1 = 0.0f;
  bf16_t* P = Ps[wave];
  const int pwoff = col * 40 + quad * 4;
  const int kswz  = (quad ^ (col & 3)) * 8;    // K/V read-side XOR
  const int wk = wave & 1;                     // q offset within diag tile /32
  const int wh = wave >> 1;                    // which 64-key half is diagonal

  const int last  = 2 * qt + 1;                // k-tiles 0..last
  const int dtile = 2 * qt + wh;               // this wave's diagonal tile

  for (int it = 0; it <= last; ++it) {
    const int buf = it & 1;
    __syncthreads();   // DMA for tile it complete; buf^1 free

    if (it < last) {   // prefetch next k-tile
      const int nk = it + 1;
      const bf16_t* kg = kg0 + (size_t)nk * 64 * DH;
      const bf16_t* vg = vg0 + nk * 64;
      bf16_t* Kd = Ks[buf ^ 1];
      bf16_t* Vd = Vs[buf ^ 1];
      load_lds16(kg,      Kd + lbase);
      load_lds16(kg + 32, Kd + 2048 + lbase);
      load_lds16(vg,      Vd + lbase);
      load_lds16(vg + 32, Vd + 2048 + lbase);
    }

    if (it <= dtile) {                 // waves 0/1 skip the final k-tile
      const bool diag = (it == dtile);
      const bf16_t* Kbuf = Ks[buf];

      // QK^T (rows=keys, cols=q) + softmax -> P
      #pragma unroll
      for (int kt = 0; kt < 4; ++kt) {
        const int R = 16 * kt + col;
        bf16x8 ka = *(const bf16x8*)(Kbuf + R * 32 + kswz);
        bf16x8 kb = *(const bf16x8*)(Kbuf + 2048 + R * 32 + kswz);
        f32x4 s0 = {}, s1 = {};
        s0 = mfma_bf16(ka, q00, s0);
        s0 = mfma_bf16(kb, q01, s0);
        s1 = mfma_bf16(ka, q10, s1);
        s1 = mfma_bf16(kb, q11, s1);
        const int kl = kt * 16 + quad * 4;
        bf16x4 p40, p41;
        #pragma unroll
        for (int r = 0; r < 4; ++r) {
          float p0 = (!diag || (kl + r <= wk * 32 + col))
                         ? __builtin_amdgcn_exp2f(s0[r]) : 0.0f;
          float p1 = (!diag || (kl + r <= wk * 32 + 16 + col))
                         ? __builtin_amdgcn_exp2f(s1[r]) : 0.0f;
          lsum0 += p0; lsum1 += p1;
          p40[r] = (bf16_t)p0; p41[r] = (bf16_t)p1;
        }
        *(bf16x4*)(P + (kt >> 1) * 640 + (kt & 1) * 16 + pwoff) = p40;
        *(bf16x4*)(P + 1280 + (kt >> 1) * 640 + (kt & 1) * 16 + pwoff) = p41;
      }

      // P B-fragments (balanced-bank b128 reads)
      bf16x8 pf00 = *(const bf16x8*)(P + col * 40 + quad * 8);
      bf16x8 pf01 = *(const bf16x8*)(P + 640 + col * 40 + quad * 8);
      bf16x8 pf10 = *(const bf16x8*)(P + 1280 + col * 40 + quad * 8);
      bf16x8 pf11 = *(const bf16x8*)(P + 1920 + col * 40 + quad * 8);

      // PV: o[d][q] += V' * P
      const bf16_t* Vbuf = Vs[buf];
      #pragma unroll
      for (int dt = 0; dt < 4; ++dt) {
        const int R = 16 * dt + col;
        bf16x8 va = *(const bf16x8*)(Vbuf + R * 32 + kswz);
        bf16x8 vb = *(const bf16x8*)(Vbuf + 2048 + R * 32 + kswz);
        o[dt][0] = mfma_bf16(va, pf00, o[dt][0]);
        o[dt][0] = mfma_bf16(vb, pf01, o[dt][0]);
        o[dt][1] = mfma_bf16(va, pf10, o[dt][1]);
        o[dt][1] = mfma_bf16(vb, pf11, o[dt][1]);
      }
    }
  }

  // finalize: reduce lsum across quads, normalize, store
  float ls0 = lsum0, ls1 = lsum1;
  ls0 += __shfl_xor(ls0, 16, 64);
  ls0 += __shfl_xor(ls0, 32, 64);
  ls1 += __shfl_xor(ls1, 16, 64);
  ls1 += __shfl_xor(ls1, 32, 64);
  const float inv0 = 1.0f / ls0;
  const float inv1 = 1.0f / ls1;
  const size_t orow0 = (size_t)(b * SEQ + qr) * DMODEL + h * DH;
  const size_t orow1 = (size_t)(b * SEQ + qr + 16) * DMODEL + h * DH;
  #pragma unroll
  for (int dt = 0; dt < 4; ++dt) {
    bf16x4 v0 = { (bf16_t)(o[dt][0][0] * inv0), (bf16_t)(o[dt][0][1] * inv0),
                  (bf16_t)(o[dt][0][2] * inv0), (bf16_t)(o[dt][0][3] * inv0) };
    bf16x4 v1 = { (bf16_t)(o[dt][1][0] * inv1), (bf16_t)(o[dt][1][1] * inv1),
                  (bf16_t)(o[dt][1][2] * inv1), (bf16_t)(o[dt][1][3] * inv1) };
    *(bf16x4*)(attn + orow0 + dt * 16 + quad * 4) = v0;
    *(bf16x4*)(attn + orow1 + dt * 16 + quad * 4) = v1;
  }
}

// ---------------- Output projection (-> f32 d_out) ----------------
__global__ __launch_bounds__(256) void out_gemm_kernel(
    const bf16_t* __restrict__ Ab, const bf16_t* __restrict__ Wob,
    float* __restrict__ out)
{
  __shared__ __align__(16) bf16_t As[128 * 32];
  __shared__ __align__(16) bf16_t Bs[128 * 32];
  f32x4 acc[4][4] = {};
  const int m0 = blockIdx.x * 128;
  const int n0 = blockIdx.y * 128;
  gemm128(Ab + (size_t)m0 * DMODEL, Wob + (size_t)n0 * DMODEL, As, Bs, acc);

  const int t = threadIdx.x;
  const int lane = t & 63, w = t >> 6;
  const int col = lane & 15, quad = lane >> 4;
  const int wm = w >> 1, wn = w & 1;
  const int mbase = m0 + wm * 64;
  const int nbase = n0 + wn * 64;

  #pragma unroll
  for (int mt = 0; mt < 4; ++mt)
    #pragma unroll
    for (int nt = 0; nt < 4; ++nt)
      #pragma unroll
      for (int r = 0; r < 4; ++r)
        out[(size_t)(mbase + mt * 16 + quad * 4 + r) * DMODEL + nbase + nt * 16 + col] =
            acc[mt][nt][r];
}

extern "C" void kernel_launch(void* const* d_in, const int* in_sizes, int n_in,
                              void* d_out, int out_size, void* d_ws, size_t ws_size,
                              hipStream_t stream)
{
  (void)in_sizes; (void)n_in; (void)out_size; (void)ws_size;
  const float* x  = (const float*)d_in[0];
  const float* Wq = (const float*)d_in[1];
  const float* Wk = (const float*)d_in[2];
  const float* Wv = (const float*)d_in[3];
  const float* Wo = (const float*)d_in[4];
  const int* tpos = (const int*)d_in[5];
  float* out = (float*)d_out;

  const size_t M1 = (size_t)1024 * 1024;
  bf16_t* xb    = (bf16_t*)d_ws;                  // 4M elems
  bf16_t* Wall  = xb + 4 * M1;                    // Wq|Wk|Wv (3M)
  bf16_t* Wob   = xb + 7 * M1;                    // 1M
  bf16_t* Qb    = xb + 8 * M1;                    // 4M  (b,h,s,d)
  bf16_t* Kb    = Qb + 4 * M1;                    // 4M  (b,h,s,d)
  bf16_t* Vt    = Kb + 4 * M1;                    // 4M  (b,h,d,s)
  bf16_t* attnb = Vt + 4 * M1;                    // 4M  (b*s, h*d)

  convert_kernel<<<dim3(4096, 1, 1), dim3(256, 1, 1), 0, stream>>>(
      x, Wq, Wk, Wv, Wo, xb);
  qkv_gemm_kernel<<<dim3(32, 24, 1), dim3(256, 1, 1), 0, stream>>>(
      xb, Wall, Qb, Kb, Vt);
  rope_kernel<<<dim3(8192, 1, 1), dim3(256, 1, 1), 0, stream>>>(Qb, Kb, tpos);
  attn_kernel<<<dim3(32, 16, 1), dim3(256, 1, 1), 0, stream>>>(
      Qb, Kb, Vt, attnb);
  out_gemm_kernel<<<dim3(32, 8, 1), dim3(256, 1, 1), 0, stream>>>(
      attnb, Wob, out);
}